// Round 6
// baseline (1460.364 us; speedup 1.0000x reference)
//
#include <hip/hip_runtime.h>

using u16 = unsigned short;
using u32 = unsigned int;

#define NS 8192
#define NQ 16384
#define SZ 64
#define STEPS 10
#define TS 64
#define TSZ (TS * SZ)      // 4096 elems per tile per array
#define NT (NS / TS)       // 128 tiles
#define NR (NT / 2)        // 64 rounds (2 tiles per round)
#define L2E 1.44269504088896340736f

typedef __attribute__((ext_vector_type(8))) _Float16 f16x8;
typedef __attribute__((ext_vector_type(4))) float f32x4;

static __device__ __forceinline__ float ex2(float x) { float r; asm("v_exp_f32 %0, %1" : "=v"(r) : "v"(x)); return r; }
static __device__ __forceinline__ float rcp_(float x) { float r; asm("v_rcp_f32 %0, %1" : "=v"(r) : "v"(x)); return r; }

static __device__ __forceinline__ u16 hbits(_Float16 h) { union { _Float16 h; u16 u; } c; c.h = h; return c.u; }
static __device__ __forceinline__ u32 pk2(float lo, float hi) {
    return (u32)hbits((_Float16)lo) | ((u32)hbits((_Float16)hi) << 16);
}
static __device__ __forceinline__ f32x4 MMH(f16x8 a, f16x8 b, f32x4 c) {
    return __builtin_amdgcn_mfma_f32_16x16x32_f16(a, b, c, 0, 0, 0);
}
static __device__ __forceinline__ f16x8 LD(const void* p) { return *(const f16x8*)p; }
static __device__ __forceinline__ float sig(float x) { return rcp_(1.f + ex2(-L2E * x)); }
static __device__ __forceinline__ float tanh_(float x) {
    float e = ex2(-2.f * L2E * x);
    return (1.f - e) * rcp_(1.f + e);
}
// wave-local LDS write->read ordering (rule #18)
static __device__ __forceinline__ void lds_fence() {
    asm volatile("s_waitcnt lgkmcnt(0)" ::: "memory");
    __builtin_amdgcn_sched_barrier(0);
}
// async global->LDS, 16B/lane, LDS dest wave-uniform + lane*16
static __device__ __forceinline__ void gload16(const void* g, void* l) {
    __builtin_amdgcn_global_load_lds(
        (const __attribute__((address_space(1))) void*)g,
        (__attribute__((address_space(3))) void*)l, 16, 0, 0);
}

// ---------------- prep: f16 hi/lo splits + tiled transpose (TS=64) + bias sum ----------------
__global__ void prep_kernel(const float* __restrict__ sup,
                            const float* __restrict__ Wih,
                            const float* __restrict__ Whh,
                            const float* __restrict__ bih,
                            const float* __restrict__ bhh,
                            u16* __restrict__ supH, u16* __restrict__ supL,
                            u16* __restrict__ supT,
                            u16* __restrict__ WiH, u16* __restrict__ WiL,
                            u16* __restrict__ WhH, u16* __restrict__ WhL,
                            float* __restrict__ bs) {
    int i = blockIdx.x * 256 + threadIdx.x;
    if (i < NS * SZ) {
        float v = sup[i];
        _Float16 hi = (_Float16)v;
        _Float16 lo = (_Float16)(v - (float)hi);
        supH[i] = hbits(hi);
        supL[i] = hbits(lo);
        int s = i >> 6, d = i & 63;
        supT[(s >> 6) * TSZ + d * TS + (s & 63)] = hbits(hi);
    }
    if (i < 4 * SZ * SZ) {
        float a = Wih[i]; _Float16 ah = (_Float16)a;
        WiH[i] = hbits(ah); WiL[i] = hbits((_Float16)(a - (float)ah));
        float b = Whh[i]; _Float16 bh = (_Float16)b;
        WhH[i] = hbits(bh); WhL[i] = hbits((_Float16)(b - (float)bh));
    }
    if (i < 4 * SZ) bs[i] = bih[i] + bhh[i];
}

// ---------------- main kernel: 16 waves/block, 4-way split-K, 4 qgroups ----------------
// w = wave id: qg = w&3 (query group, 16 queries), quarter = w>>2.
// Quarter p handles tile (2r + (p>>1)) of each round pair, s-half (p&1) (32 rows).
// Lead waves (quarter 0) own merge/gates/LSTM/output for their qgroup.
__global__ __launch_bounds__(1024, 4) void attlstm_kernel(
    const float* __restrict__ queries,
    const u16* __restrict__ supH, const u16* __restrict__ supL,
    const u16* __restrict__ supT,
    const u16* __restrict__ WiH, const u16* __restrict__ WiL,
    const u16* __restrict__ WhH, const u16* __restrict__ WhL,
    const float* __restrict__ bsum,
    float* __restrict__ out) {
    __shared__ __align__(16) u16 stage[4][3][TSZ];   // 96KB: 4 tile-slots x {supH,supL,supT}
    __shared__ __align__(16) u32 P_lds[16][512];     // 32KB: per-wave P (only 64B/row used)
    __shared__ __align__(16) u16 hsl[4][2048];       // 16KB: per-qgroup h hi[0..2047B]/lo[2048..]
    __shared__ __align__(16) float bs_lds[256];      // 1KB

    const int tid = threadIdx.x;
    const int w = tid >> 6;
    const int l = tid & 63;
    const int qg = w & 3;
    const int quarter = w >> 2;
    const int tsel = quarter >> 1;     // which tile of the round pair
    const int shalf = quarter & 1;     // which 32-row s-half of that tile
    const bool lead = (quarter == 0);
    const int q = l & 15;
    const int g = l >> 4;
    const int qrow = blockIdx.x * 64 + qg * 16 + q;
    const u32 swz = (u32)(q & 7) << 4;

    if (tid < 256) bs_lds[tid] = bsum[tid];

    // staging: 48 1KB-chunks per round pair (2 tiles x 3 arrays x 8 row-blocks);
    // wave w stages chunks c = w, w+16, w+32. Source pre-swizzled (rule #21).
    const u16* gsrc[3]; int inoff[3]; int ctsel[3];
#pragma unroll
    for (int j = 0; j < 3; ++j) {
        int c = w + 16 * j;
        ctsel[j] = c / 24;
        int rem = c - 24 * ctsel[j];
        int a = rem >> 3, s8 = rem & 7;
        int srcoff = (s8 * 8 + (l >> 3)) * SZ + ((l & 7) ^ (l >> 3)) * 8;
        gsrc[j] = ((a == 0) ? supH : (a == 1) ? supL : supT) + srcoff;
        inoff[j] = a * TSZ + s8 * 512;
    }
    u16* stg = &stage[0][0][0];
    char* hslb = (char*)&hsl[qg][0];
    char* pw = (char*)&P_lds[w][0];

    float qv[16], hh[16], cc[16];
    f16x8 qfh0, qfh1, qfl0, qfl1;
    if (lead) {
#pragma unroll
        for (int s4 = 0; s4 < 4; ++s4) {
            f32x4 v = *(const f32x4*)&queries[qrow * SZ + 16 * s4 + 4 * g];
#pragma unroll
            for (int jj = 0; jj < 4; ++jj) {
                qv[4 * s4 + jj] = v[jj];
                hh[4 * s4 + jj] = 0.f;
                cc[4 * s4 + jj] = 0.f;
            }
            _Float16 c0 = (_Float16)v[0], c1 = (_Float16)v[1], c2 = (_Float16)v[2], c3 = (_Float16)v[3];
            uint2 whi, wlo;
            whi.x = (u32)hbits(c0) | ((u32)hbits(c1) << 16);
            whi.y = (u32)hbits(c2) | ((u32)hbits(c3) << 16);
            wlo.x = pk2(v[0] - (float)c0, v[1] - (float)c1);
            wlo.y = pk2(v[2] - (float)c2, v[3] - (float)c3);
            u32 b = q * 128 + ((32u * s4 + 8u * g) ^ swz);
            *(uint2*)(hslb + b) = whi;
            *(uint2*)(hslb + 2048 + b) = wlo;
        }
        lds_fence();
        qfh0 = LD(hslb + q * 128 + ((16u * g) ^ swz));
        qfh1 = LD(hslb + q * 128 + ((16u * g + 64u) ^ swz));
        qfl0 = LD(hslb + 2048 + q * 128 + ((16u * g) ^ swz));
        qfl1 = LD(hslb + 2048 + q * 128 + ((16u * g + 64u) ^ swz));
    }

#pragma unroll 1
    for (int step = 0; step < STEPS; ++step) {
        // ---- lead: h = h_hat + queries, hi/lo -> hsl[qg] ----
        if (lead) {
#pragma unroll
            for (int s4 = 0; s4 < 4; ++s4) {
                float h0 = hh[4 * s4 + 0] + qv[4 * s4 + 0];
                float h1 = hh[4 * s4 + 1] + qv[4 * s4 + 1];
                float h2 = hh[4 * s4 + 2] + qv[4 * s4 + 2];
                float h3 = hh[4 * s4 + 3] + qv[4 * s4 + 3];
                _Float16 a0 = (_Float16)h0, a1 = (_Float16)h1, a2 = (_Float16)h2, a3 = (_Float16)h3;
                uint2 whi, wlo;
                whi.x = (u32)hbits(a0) | ((u32)hbits(a1) << 16);
                whi.y = (u32)hbits(a2) | ((u32)hbits(a3) << 16);
                wlo.x = pk2(h0 - (float)a0, h1 - (float)a1);
                wlo.y = pk2(h2 - (float)a2, h3 - (float)a3);
                u32 b = q * 128 + ((32u * s4 + 8u * g) ^ swz);
                *(uint2*)(hslb + b) = whi;
                *(uint2*)(hslb + 2048 + b) = wlo;
            }
        }
        __syncthreads();
        const f16x8 bh0 = LD(hslb + q * 128 + ((16u * g) ^ swz));
        const f16x8 bh1 = LD(hslb + q * 128 + ((16u * g + 64u) ^ swz));
        const f16x8 bl0 = LD(hslb + 2048 + q * 128 + ((16u * g) ^ swz));
        const f16x8 bl1 = LD(hslb + 2048 + q * 128 + ((16u * g + 64u) ^ swz));

        // ---- prologue: stage tiles 0,1 into slots 0,1 ----
#pragma unroll
        for (int j = 0; j < 3; ++j)
            gload16(gsrc[j] + ctsel[j] * TSZ, stg + ctsel[j] * 12288 + inoff[j]);
        __syncthreads();

        float m = -1e30f, mL = -1.5e30f, lsum = 0.f;
        f32x4 Oa[4] = {{0, 0, 0, 0}, {0, 0, 0, 0}, {0, 0, 0, 0}, {0, 0, 0, 0}};

#pragma unroll 1
        for (int r = 0; r < NR; ++r) {
            // ---- prefetch next round's pair ----
            if (r < NR - 1) {
#pragma unroll
                for (int j = 0; j < 3; ++j) {
                    int t = 2 * r + 2 + ctsel[j];
                    gload16(gsrc[j] + t * TSZ, stg + (t & 3) * 12288 + inoff[j]);
                }
            }
            const int myslot = (2 * r + tsel) & 3;
            const char* sH = (const char*)(stg + myslot * 12288);
            const char* sL = sH + TSZ * 2;
            const char* sT = sH + 2 * TSZ * 2;
            // ---- S^T = sup_rows . h (3-product hi/lo split), 32 s-rows ----
            f32x4 sv[2];
#pragma unroll
            for (int sub = 0; sub < 2; ++sub) {
                u32 rb = (u32)(16 * (2 * shalf + sub) + q) * 128;
                f16x8 aH0 = LD(sH + rb + ((16u * g) ^ swz));
                f16x8 aH1 = LD(sH + rb + ((16u * g + 64u) ^ swz));
                f16x8 aL0 = LD(sL + rb + ((16u * g) ^ swz));
                f16x8 aL1 = LD(sL + rb + ((16u * g + 64u) ^ swz));
                f32x4 a = {0, 0, 0, 0};
                a = MMH(aH0, bh0, a); a = MMH(aH1, bh1, a);
                a = MMH(aH0, bl0, a); a = MMH(aH1, bl1, a);
                a = MMH(aL0, bh0, a); a = MMH(aL1, bh1, a);
                sv[sub] = a;
            }
            // ---- online softmax with defer-max (T13) ----
            float tm = fmaxf(fmaxf(fmaxf(sv[0][0], sv[0][1]), fmaxf(sv[0][2], sv[0][3])),
                             fmaxf(fmaxf(sv[1][0], sv[1][1]), fmaxf(sv[1][2], sv[1][3])));
            tm = fmaxf(tm, __shfl_xor(tm, 16));
            tm = fmaxf(tm, __shfl_xor(tm, 32));
            if (__any(tm > m + 5.5f)) {
                float mn = fmaxf(m, tm);
                float sc = ex2((m - mn) * L2E);
                lsum *= sc;
                Oa[0] *= sc; Oa[1] *= sc; Oa[2] *= sc; Oa[3] *= sc;
                m = mn; mL = m * L2E;
            }
            // ---- P = exp(S - m) -> f16 -> swizzled per-wave P_lds ----
#pragma unroll
            for (int sub = 0; sub < 2; ++sub) {
                float p0 = ex2(sv[sub][0] * L2E - mL);
                float p1 = ex2(sv[sub][1] * L2E - mL);
                float p2 = ex2(sv[sub][2] * L2E - mL);
                float p3 = ex2(sv[sub][3] * L2E - mL);
                lsum += (p0 + p1) + (p2 + p3);
                uint2 wv; wv.x = pk2(p0, p1); wv.y = pk2(p2, p3);
                *(uint2*)(pw + q * 128 + ((32u * sub + 8u * g) ^ swz)) = wv;
            }
            lds_fence();
            // ---- O^T += supT(s-half) . P : K=32 exactly one MFMA per dsub ----
            f16x8 pb = LD(pw + q * 128 + ((16u * g) ^ swz));
            u32 kbT = (16u * g + 64u * shalf) ^ swz;
#pragma unroll
            for (int dsub = 0; dsub < 4; ++dsub) {
                f16x8 aT = LD(sT + (u32)(16 * dsub + q) * 128 + kbT);
                Oa[dsub] = MMH(aT, pb, Oa[dsub]);
            }
            __syncthreads();   // drains vmcnt(0): next pair staged; slots rotate
        }
        lsum += __shfl_xor(lsum, 16);
        lsum += __shfl_xor(lsum, 32);

        // ---- merge 4 split-K partials (scratch aliases stage; barrier-separated) ----
        float* mg = (float*)stg;
        float* mine = mg + (u32)(w * 64 + l) * 20;
        *(f32x4*)(mine + 0) = Oa[0];
        *(f32x4*)(mine + 4) = Oa[1];
        *(f32x4*)(mine + 8) = Oa[2];
        *(f32x4*)(mine + 12) = Oa[3];
        mine[16] = m; mine[17] = lsum;
        __syncthreads();

        if (lead) {
#pragma unroll
            for (int k = 1; k < 4; ++k) {
                const float* oth = mg + (u32)((w + 4 * k) * 64 + l) * 20;
                f32x4 Ob0 = *(const f32x4*)(oth + 0);
                f32x4 Ob1 = *(const f32x4*)(oth + 4);
                f32x4 Ob2 = *(const f32x4*)(oth + 8);
                f32x4 Ob3 = *(const f32x4*)(oth + 12);
                float mo = oth[16], lo_ = oth[17];
                float M = fmaxf(m, mo);
                float sA = ex2((m - M) * L2E), sB = ex2((mo - M) * L2E);
                lsum = lsum * sA + lo_ * sB;
                Oa[0] = Oa[0] * sA + Ob0 * sB;
                Oa[1] = Oa[1] * sA + Ob1 * sB;
                Oa[2] = Oa[2] * sA + Ob2 * sB;
                Oa[3] = Oa[3] * sA + Ob3 * sB;
                m = M;
            }
            float inv = rcp_(lsum);

            // ---- hr = h + readout, hi/lo -> hsl[qg] (wave-local round-trip) ----
#pragma unroll
            for (int s4 = 0; s4 < 4; ++s4) {
                float r0 = hh[4 * s4 + 0] + qv[4 * s4 + 0] + Oa[s4][0] * inv;
                float r1 = hh[4 * s4 + 1] + qv[4 * s4 + 1] + Oa[s4][1] * inv;
                float r2 = hh[4 * s4 + 2] + qv[4 * s4 + 2] + Oa[s4][2] * inv;
                float r3 = hh[4 * s4 + 3] + qv[4 * s4 + 3] + Oa[s4][3] * inv;
                _Float16 a0 = (_Float16)r0, a1 = (_Float16)r1, a2 = (_Float16)r2, a3 = (_Float16)r3;
                uint2 whi, wlo;
                whi.x = (u32)hbits(a0) | ((u32)hbits(a1) << 16);
                whi.y = (u32)hbits(a2) | ((u32)hbits(a3) << 16);
                wlo.x = pk2(r0 - (float)a0, r1 - (float)a1);
                wlo.y = pk2(r2 - (float)a2, r3 - (float)a3);
                u32 b = q * 128 + ((32u * s4 + 8u * g) ^ swz);
                *(uint2*)(hslb + b) = whi;
                *(uint2*)(hslb + 2048 + b) = wlo;
            }
            lds_fence();
            const f16x8 rh0 = LD(hslb + q * 128 + ((16u * g) ^ swz));
            const f16x8 rh1 = LD(hslb + q * 128 + ((16u * g + 64u) ^ swz));
            const f16x8 rl0 = LD(hslb + 2048 + q * 128 + ((16u * g) ^ swz));
            const f16x8 rl1 = LD(hslb + 2048 + q * 128 + ((16u * g + 64u) ^ swz));

            // ---- gates^T = Wstack . [queries; hr] + bias; LSTM elementwise ----
#pragma unroll
            for (int s4 = 0; s4 < 4; ++s4) {
                f32x4 ga[4];
#pragma unroll
                for (int ch = 0; ch < 4; ++ch) {  // 0=i 1=f 2=g 3=o
                    int u_ = 4 * ch + s4;
                    f32x4 a = *(const f32x4*)&bs_lds[16 * u_ + 4 * g];
                    const u16* wiH = WiH + (16 * u_ + q) * SZ + 8 * g;
                    const u16* wiL = WiL + (16 * u_ + q) * SZ + 8 * g;
                    const u16* whH = WhH + (16 * u_ + q) * SZ + 8 * g;
                    const u16* whL = WhL + (16 * u_ + q) * SZ + 8 * g;
                    f16x8 w0 = LD(wiH), w1 = LD(wiH + 32);
                    a = MMH(w0, qfh0, a); a = MMH(w1, qfh1, a);
                    a = MMH(w0, qfl0, a); a = MMH(w1, qfl1, a);
                    a = MMH(LD(wiL), qfh0, a); a = MMH(LD(wiL + 32), qfh1, a);
                    f16x8 v0 = LD(whH), v1 = LD(whH + 32);
                    a = MMH(v0, rh0, a); a = MMH(v1, rh1, a);
                    a = MMH(v0, rl0, a); a = MMH(v1, rl1, a);
                    a = MMH(LD(whL), rh0, a); a = MMH(LD(whL + 32), rh1, a);
                    ga[ch] = a;
                }
#pragma unroll
                for (int jj = 0; jj < 4; ++jj) {
                    int tt = 4 * s4 + jj;
                    float gi = sig(ga[0][jj]);
                    float gf = sig(ga[1][jj]);
                    float gg = tanh_(ga[2][jj]);
                    float go = sig(ga[3][jj]);
                    float cn = gf * cc[tt] + gi * gg;
                    cc[tt] = cn;
                    hh[tt] = go * tanh_(cn);
                }
            }
        }
    }

    // ---- out = h_hat + queries (lead only) ----
    if (lead) {
#pragma unroll
        for (int s4 = 0; s4 < 4; ++s4) {
            f32x4 v;
#pragma unroll
            for (int jj = 0; jj < 4; ++jj) v[jj] = hh[4 * s4 + jj] + qv[4 * s4 + jj];
            *(f32x4*)&out[qrow * SZ + 16 * s4 + 4 * g] = v;
        }
    }
}

extern "C" void kernel_launch(void* const* d_in, const int* in_sizes, int n_in,
                              void* d_out, int out_size, void* d_ws, size_t ws_size,
                              hipStream_t stream) {
    const float* support = (const float*)d_in[0];
    const float* queries = (const float*)d_in[1];
    const float* W_ih = (const float*)d_in[2];
    const float* W_hh = (const float*)d_in[3];
    const float* b_ih = (const float*)d_in[4];
    const float* b_hh = (const float*)d_in[5];
    float* out = (float*)d_out;

    u16* supH = (u16*)d_ws;                    // 8192*64
    u16* supL = supH + NS * SZ;                // 8192*64
    u16* supT = supL + NS * SZ;                // 8192*64 (tiled transpose, hi)
    u16* WiH = supT + NS * SZ;                 // 256*64
    u16* WiL = WiH + 4 * SZ * SZ;
    u16* WhH = WiL + 4 * SZ * SZ;
    u16* WhL = WhH + 4 * SZ * SZ;
    float* bs = (float*)(WhL + 4 * SZ * SZ);   // 256

    prep_kernel<<<(NS * SZ) / 256, 256, 0, stream>>>(support, W_ih, W_hh, b_ih, b_hh,
                                                     supH, supL, supT, WiH, WiL, WhH, WhL, bs);
    attlstm_kernel<<<NQ / 64, 1024, 0, stream>>>(queries, supH, supL, supT,
                                                 WiH, WiL, WhH, WhL, bs, out);
}

// Round 7
// 1315.809 us; speedup vs baseline: 1.1099x; 1.1099x over previous
//
#include <hip/hip_runtime.h>

using u16 = unsigned short;
using u32 = unsigned int;

#define NS 8192
#define NQ 16384
#define SZ 64
#define STEPS 10
#define TS 64
#define TSZ (TS * SZ)      // 4096 elems per tile per array
#define NT (NS / TS)       // 128 tiles
#define NR (NT / 2)        // 64 rounds (2 tiles per round)
#define L2E 1.44269504088896340736f

typedef __attribute__((ext_vector_type(8))) _Float16 f16x8;
typedef __attribute__((ext_vector_type(4))) float f32x4;

static __device__ __forceinline__ float ex2(float x) { float r; asm("v_exp_f32 %0, %1" : "=v"(r) : "v"(x)); return r; }
static __device__ __forceinline__ float rcp_(float x) { float r; asm("v_rcp_f32 %0, %1" : "=v"(r) : "v"(x)); return r; }

static __device__ __forceinline__ u16 hbits(_Float16 h) { union { _Float16 h; u16 u; } c; c.h = h; return c.u; }
static __device__ __forceinline__ u32 pk2(float lo, float hi) {
    return (u32)hbits((_Float16)lo) | ((u32)hbits((_Float16)hi) << 16);
}
static __device__ __forceinline__ f32x4 MMH(f16x8 a, f16x8 b, f32x4 c) {
    return __builtin_amdgcn_mfma_f32_16x16x32_f16(a, b, c, 0, 0, 0);
}
static __device__ __forceinline__ f16x8 LD(const void* p) { return *(const f16x8*)p; }
static __device__ __forceinline__ float sig(float x) { return rcp_(1.f + ex2(-L2E * x)); }
static __device__ __forceinline__ float tanh_(float x) {
    float e = ex2(-2.f * L2E * x);
    return (1.f - e) * rcp_(1.f + e);
}
// wave-local LDS write->read ordering (rule #18)
static __device__ __forceinline__ void lds_fence() {
    asm volatile("s_waitcnt lgkmcnt(0)" ::: "memory");
    __builtin_amdgcn_sched_barrier(0);
}
// async global->LDS, 16B/lane, LDS dest wave-uniform + lane*16
static __device__ __forceinline__ void gload16(const void* g, void* l) {
    __builtin_amdgcn_global_load_lds(
        (const __attribute__((address_space(1))) void*)g,
        (__attribute__((address_space(3))) void*)l, 16, 0, 0);
}

// ---------------- prep: f16 hi/lo splits + tiled transpose (TS=64) + bias sum ----------------
__global__ void prep_kernel(const float* __restrict__ sup,
                            const float* __restrict__ Wih,
                            const float* __restrict__ Whh,
                            const float* __restrict__ bih,
                            const float* __restrict__ bhh,
                            u16* __restrict__ supH, u16* __restrict__ supL,
                            u16* __restrict__ supT,
                            u16* __restrict__ WiH, u16* __restrict__ WiL,
                            u16* __restrict__ WhH, u16* __restrict__ WhL,
                            float* __restrict__ bs) {
    int i = blockIdx.x * 256 + threadIdx.x;
    if (i < NS * SZ) {
        float v = sup[i];
        _Float16 hi = (_Float16)v;
        _Float16 lo = (_Float16)(v - (float)hi);
        supH[i] = hbits(hi);
        supL[i] = hbits(lo);
        int s = i >> 6, d = i & 63;
        supT[(s >> 6) * TSZ + d * TS + (s & 63)] = hbits(hi);
    }
    if (i < 4 * SZ * SZ) {
        float a = Wih[i]; _Float16 ah = (_Float16)a;
        WiH[i] = hbits(ah); WiL[i] = hbits((_Float16)(a - (float)ah));
        float b = Whh[i]; _Float16 bh = (_Float16)b;
        WhH[i] = hbits(bh); WhL[i] = hbits((_Float16)(b - (float)bh));
    }
    if (i < 4 * SZ) bs[i] = bih[i] + bhh[i];
}

// ---------------- main kernel: 16 waves/block, 4-way split-K, DISTRIBUTED epilogue ----------------
// w = wave id: qg = w&3 (query group, 16 queries), quarter = w>>2.
// Tile loop: quarter p handles tile (2r + (p>>1)) of each round pair, s-half (p&1).
// Epilogue: wave (qg,p) owns LSTM-state slice s4=p (d in [16p,16p+16)): qv/hh/cc[4],
// merges only Oa[p] across the 4 partials, computes gate rows u_=4*ch+p, writes out slice.
__global__ __launch_bounds__(1024) void attlstm_kernel(
    const float* __restrict__ queries,
    const u16* __restrict__ supH, const u16* __restrict__ supL,
    const u16* __restrict__ supT,
    const u16* __restrict__ WiH, const u16* __restrict__ WiL,
    const u16* __restrict__ WhH, const u16* __restrict__ WhL,
    const float* __restrict__ bsum,
    float* __restrict__ out) {
    __shared__ __align__(16) u16 stage[4][3][TSZ];   // 96KB: 4 tile-slots x {supH,supL,supT}
    __shared__ __align__(16) u32 P_lds[16][512];     // 32KB: per-wave P
    __shared__ __align__(16) u16 hsl[4][2048];       // 16KB: per-qgroup h hi/lo
    __shared__ __align__(16) float bs_lds[256];      // 1KB

    const int tid = threadIdx.x;
    const int w = tid >> 6;
    const int l = tid & 63;
    const int qg = w & 3;
    const int quarter = w >> 2;
    const int tsel = quarter >> 1;     // which tile of the round pair
    const int shalf = quarter & 1;     // which 32-row s-half of that tile
    const int q = l & 15;
    const int g = l >> 4;
    const int qrow = blockIdx.x * 64 + qg * 16 + q;
    const u32 swz = (u32)(q & 7) << 4;
    const u32 bsl = (u32)q * 128 + ((32u * (u32)quarter + 8u * (u32)g) ^ swz);  // this wave's hsl slice slot

    if (tid < 256) bs_lds[tid] = bsum[tid];

    // staging: 48 1KB-chunks per round pair (2 tiles x 3 arrays x 8 row-blocks);
    // wave w stages chunks c = w, w+16, w+32. Source pre-swizzled (rule #21).
    const u16* gsrc[3]; int inoff[3]; int ctsel[3];
#pragma unroll
    for (int j = 0; j < 3; ++j) {
        int c = w + 16 * j;
        ctsel[j] = c / 24;
        int rem = c - 24 * ctsel[j];
        int a = rem >> 3, s8 = rem & 7;
        int srcoff = (s8 * 8 + (l >> 3)) * SZ + ((l & 7) ^ (l >> 3)) * 8;
        gsrc[j] = ((a == 0) ? supH : (a == 1) ? supL : supT) + srcoff;
        inoff[j] = a * TSZ + s8 * 512;
    }
    u16* stg = &stage[0][0][0];
    char* hslb = (char*)&hsl[qg][0];
    char* pw = (char*)&P_lds[w][0];

    // ---- per-wave LSTM-state slice (s4 = quarter): d = 16*quarter + 4g + jj ----
    float qv[4], hh[4], cc[4];
    {
        f32x4 v = *(const f32x4*)&queries[qrow * SZ + 16 * quarter + 4 * g];
#pragma unroll
        for (int jj = 0; jj < 4; ++jj) { qv[jj] = v[jj]; hh[jj] = 0.f; cc[jj] = 0.f; }
        _Float16 c0 = (_Float16)v[0], c1 = (_Float16)v[1], c2 = (_Float16)v[2], c3 = (_Float16)v[3];
        uint2 whi, wlo;
        whi.x = (u32)hbits(c0) | ((u32)hbits(c1) << 16);
        whi.y = (u32)hbits(c2) | ((u32)hbits(c3) << 16);
        wlo.x = pk2(v[0] - (float)c0, v[1] - (float)c1);
        wlo.y = pk2(v[2] - (float)c2, v[3] - (float)c3);
        *(uint2*)(hslb + bsl) = whi;
        *(uint2*)(hslb + 2048 + bsl) = wlo;
    }
    __syncthreads();
    const f16x8 qfh0 = LD(hslb + q * 128 + ((16u * g) ^ swz));
    const f16x8 qfh1 = LD(hslb + q * 128 + ((16u * g + 64u) ^ swz));
    const f16x8 qfl0 = LD(hslb + 2048 + q * 128 + ((16u * g) ^ swz));
    const f16x8 qfl1 = LD(hslb + 2048 + q * 128 + ((16u * g + 64u) ^ swz));

#pragma unroll 1
    for (int step = 0; step < STEPS; ++step) {
        __syncthreads();   // all waves done reading hsl (q/hr frags) before overwrite
        // ---- h = h_hat + queries (slice) -> hsl[qg] ----
        {
            float h0 = hh[0] + qv[0], h1 = hh[1] + qv[1], h2 = hh[2] + qv[2], h3 = hh[3] + qv[3];
            _Float16 a0 = (_Float16)h0, a1 = (_Float16)h1, a2 = (_Float16)h2, a3 = (_Float16)h3;
            uint2 whi, wlo;
            whi.x = (u32)hbits(a0) | ((u32)hbits(a1) << 16);
            whi.y = (u32)hbits(a2) | ((u32)hbits(a3) << 16);
            wlo.x = pk2(h0 - (float)a0, h1 - (float)a1);
            wlo.y = pk2(h2 - (float)a2, h3 - (float)a3);
            *(uint2*)(hslb + bsl) = whi;
            *(uint2*)(hslb + 2048 + bsl) = wlo;
        }
        __syncthreads();
        const f16x8 bh0 = LD(hslb + q * 128 + ((16u * g) ^ swz));
        const f16x8 bh1 = LD(hslb + q * 128 + ((16u * g + 64u) ^ swz));
        const f16x8 bl0 = LD(hslb + 2048 + q * 128 + ((16u * g) ^ swz));
        const f16x8 bl1 = LD(hslb + 2048 + q * 128 + ((16u * g + 64u) ^ swz));

        // ---- prologue: stage tiles 0,1 into slots 0,1 ----
#pragma unroll
        for (int j = 0; j < 3; ++j)
            gload16(gsrc[j] + ctsel[j] * TSZ, stg + ctsel[j] * 12288 + inoff[j]);
        __syncthreads();

        float m = -1e30f, mL = -1.5e30f, lsum = 0.f;
        f32x4 Oa[4] = {{0, 0, 0, 0}, {0, 0, 0, 0}, {0, 0, 0, 0}, {0, 0, 0, 0}};

#pragma unroll 1
        for (int r = 0; r < NR; ++r) {
            // ---- prefetch next round's pair ----
            if (r < NR - 1) {
#pragma unroll
                for (int j = 0; j < 3; ++j) {
                    int t = 2 * r + 2 + ctsel[j];
                    gload16(gsrc[j] + t * TSZ, stg + (t & 3) * 12288 + inoff[j]);
                }
            }
            const int myslot = (2 * r + tsel) & 3;
            const char* sH = (const char*)(stg + myslot * 12288);
            const char* sL = sH + TSZ * 2;
            const char* sT = sH + 2 * TSZ * 2;
            // ---- S^T = sup_rows . h (3-product hi/lo split), 32 s-rows ----
            f32x4 sv[2];
#pragma unroll
            for (int sub = 0; sub < 2; ++sub) {
                u32 rb = (u32)(16 * (2 * shalf + sub) + q) * 128;
                f16x8 aH0 = LD(sH + rb + ((16u * g) ^ swz));
                f16x8 aH1 = LD(sH + rb + ((16u * g + 64u) ^ swz));
                f16x8 aL0 = LD(sL + rb + ((16u * g) ^ swz));
                f16x8 aL1 = LD(sL + rb + ((16u * g + 64u) ^ swz));
                f32x4 a = {0, 0, 0, 0};
                a = MMH(aH0, bh0, a); a = MMH(aH1, bh1, a);
                a = MMH(aH0, bl0, a); a = MMH(aH1, bl1, a);
                a = MMH(aL0, bh0, a); a = MMH(aL1, bh1, a);
                sv[sub] = a;
            }
            // ---- online softmax with defer-max (T13) ----
            float tm = fmaxf(fmaxf(fmaxf(sv[0][0], sv[0][1]), fmaxf(sv[0][2], sv[0][3])),
                             fmaxf(fmaxf(sv[1][0], sv[1][1]), fmaxf(sv[1][2], sv[1][3])));
            tm = fmaxf(tm, __shfl_xor(tm, 16));
            tm = fmaxf(tm, __shfl_xor(tm, 32));
            if (__any(tm > m + 5.5f)) {
                float mn = fmaxf(m, tm);
                float sc = ex2((m - mn) * L2E);
                lsum *= sc;
                Oa[0] *= sc; Oa[1] *= sc; Oa[2] *= sc; Oa[3] *= sc;
                m = mn; mL = m * L2E;
            }
            // ---- P = exp(S - m) -> f16 -> swizzled per-wave P_lds ----
#pragma unroll
            for (int sub = 0; sub < 2; ++sub) {
                float p0 = ex2(sv[sub][0] * L2E - mL);
                float p1 = ex2(sv[sub][1] * L2E - mL);
                float p2 = ex2(sv[sub][2] * L2E - mL);
                float p3 = ex2(sv[sub][3] * L2E - mL);
                lsum += (p0 + p1) + (p2 + p3);
                uint2 wv; wv.x = pk2(p0, p1); wv.y = pk2(p2, p3);
                *(uint2*)(pw + q * 128 + ((32u * sub + 8u * g) ^ swz)) = wv;
            }
            lds_fence();
            // ---- O^T += supT(s-half) . P : K=32 exactly one MFMA per dsub ----
            f16x8 pb = LD(pw + q * 128 + ((16u * g) ^ swz));
            u32 kbT = (16u * g + 64u * shalf) ^ swz;
#pragma unroll
            for (int dsub = 0; dsub < 4; ++dsub) {
                f16x8 aT = LD(sT + (u32)(16 * dsub + q) * 128 + kbT);
                Oa[dsub] = MMH(aT, pb, Oa[dsub]);
            }
            __syncthreads();   // drains vmcnt(0): next pair staged; slots rotate
        }
        lsum += __shfl_xor(lsum, 16);
        lsum += __shfl_xor(lsum, 32);

        // ---- write split-K partials (scratch aliases stage; barrier-separated) ----
        float* mg = (float*)stg;
        float* mine = mg + (u32)(w * 64 + l) * 20;
        *(f32x4*)(mine + 0) = Oa[0];
        *(f32x4*)(mine + 4) = Oa[1];
        *(f32x4*)(mine + 8) = Oa[2];
        *(f32x4*)(mine + 12) = Oa[3];
        mine[16] = m; mine[17] = lsum;
        __syncthreads();

        // ---- distributed merge: every wave merges only its Oa[quarter] slice ----
        float mk[4], lk[4];
        f32x4 Ok[4];
#pragma unroll
        for (int k = 0; k < 4; ++k) {
            const float* oth = mg + (u32)((qg + 4 * k) * 64 + l) * 20;
            Ok[k] = *(const f32x4*)(oth + 4 * quarter);
            mk[k] = oth[16]; lk[k] = oth[17];
        }
        float M = fmaxf(fmaxf(mk[0], mk[1]), fmaxf(mk[2], mk[3]));
        f32x4 Op = {0, 0, 0, 0};
        float ls = 0.f;
#pragma unroll
        for (int k = 0; k < 4; ++k) {
            float sk = ex2((mk[k] - M) * L2E);
            ls += lk[k] * sk;
            Op += Ok[k] * sk;
        }
        float inv = rcp_(ls);

        // ---- hr = h + readout (slice) -> hsl[qg] ----
        {
            float r0 = hh[0] + qv[0] + Op[0] * inv;
            float r1 = hh[1] + qv[1] + Op[1] * inv;
            float r2 = hh[2] + qv[2] + Op[2] * inv;
            float r3 = hh[3] + qv[3] + Op[3] * inv;
            _Float16 a0 = (_Float16)r0, a1 = (_Float16)r1, a2 = (_Float16)r2, a3 = (_Float16)r3;
            uint2 whi, wlo;
            whi.x = (u32)hbits(a0) | ((u32)hbits(a1) << 16);
            whi.y = (u32)hbits(a2) | ((u32)hbits(a3) << 16);
            wlo.x = pk2(r0 - (float)a0, r1 - (float)a1);
            wlo.y = pk2(r2 - (float)a2, r3 - (float)a3);
            *(uint2*)(hslb + bsl) = whi;
            *(uint2*)(hslb + 2048 + bsl) = wlo;
        }
        __syncthreads();
        const f16x8 rh0 = LD(hslb + q * 128 + ((16u * g) ^ swz));
        const f16x8 rh1 = LD(hslb + q * 128 + ((16u * g + 64u) ^ swz));
        const f16x8 rl0 = LD(hslb + 2048 + q * 128 + ((16u * g) ^ swz));
        const f16x8 rl1 = LD(hslb + 2048 + q * 128 + ((16u * g + 64u) ^ swz));

        // ---- gates (distributed): wave computes rows u_=4*ch+quarter; LSTM on slice ----
        f32x4 ga[4];
#pragma unroll
        for (int ch = 0; ch < 4; ++ch) {  // 0=i 1=f 2=g 3=o
            int u_ = 4 * ch + quarter;
            f32x4 a = *(const f32x4*)&bs_lds[16 * u_ + 4 * g];
            const u16* wiH = WiH + (16 * u_ + q) * SZ + 8 * g;
            const u16* wiL = WiL + (16 * u_ + q) * SZ + 8 * g;
            const u16* whH = WhH + (16 * u_ + q) * SZ + 8 * g;
            const u16* whL = WhL + (16 * u_ + q) * SZ + 8 * g;
            f16x8 w0 = LD(wiH), w1 = LD(wiH + 32);
            a = MMH(w0, qfh0, a); a = MMH(w1, qfh1, a);
            a = MMH(w0, qfl0, a); a = MMH(w1, qfl1, a);
            a = MMH(LD(wiL), qfh0, a); a = MMH(LD(wiL + 32), qfh1, a);
            f16x8 v0 = LD(whH), v1 = LD(whH + 32);
            a = MMH(v0, rh0, a); a = MMH(v1, rh1, a);
            a = MMH(v0, rl0, a); a = MMH(v1, rl1, a);
            a = MMH(LD(whL), rh0, a); a = MMH(LD(whL + 32), rh1, a);
            ga[ch] = a;
        }
#pragma unroll
        for (int jj = 0; jj < 4; ++jj) {
            float gi = sig(ga[0][jj]);
            float gf = sig(ga[1][jj]);
            float gg = tanh_(ga[2][jj]);
            float go = sig(ga[3][jj]);
            float cn = gf * cc[jj] + gi * gg;
            cc[jj] = cn;
            hh[jj] = go * tanh_(cn);
        }
    }

    // ---- out = h_hat + queries (slice) ----
    {
        f32x4 v;
#pragma unroll
        for (int jj = 0; jj < 4; ++jj) v[jj] = hh[jj] + qv[jj];
        *(f32x4*)&out[qrow * SZ + 16 * quarter + 4 * g] = v;
    }
}

extern "C" void kernel_launch(void* const* d_in, const int* in_sizes, int n_in,
                              void* d_out, int out_size, void* d_ws, size_t ws_size,
                              hipStream_t stream) {
    const float* support = (const float*)d_in[0];
    const float* queries = (const float*)d_in[1];
    const float* W_ih = (const float*)d_in[2];
    const float* W_hh = (const float*)d_in[3];
    const float* b_ih = (const float*)d_in[4];
    const float* b_hh = (const float*)d_in[5];
    float* out = (float*)d_out;

    u16* supH = (u16*)d_ws;                    // 8192*64
    u16* supL = supH + NS * SZ;                // 8192*64
    u16* supT = supL + NS * SZ;                // 8192*64 (tiled transpose, hi)
    u16* WiH = supT + NS * SZ;                 // 256*64
    u16* WiL = WiH + 4 * SZ * SZ;
    u16* WhH = WiL + 4 * SZ * SZ;
    u16* WhL = WhH + 4 * SZ * SZ;
    float* bs = (float*)(WhL + 4 * SZ * SZ);   // 256

    prep_kernel<<<(NS * SZ) / 256, 256, 0, stream>>>(support, W_ih, W_hh, b_ih, b_hh,
                                                     supH, supL, supT, WiH, WiL, WhH, WhL, bs);
    attlstm_kernel<<<NQ / 64, 1024, 0, stream>>>(queries, supH, supL, supT,
                                                 WiH, WiL, WhH, WhL, bs, out);
}